// Round 5
// baseline (449.472 us; speedup 1.0000x reference)
//
#include <hip/hip_runtime.h>
#include <math.h>

#define LOOKBACK 336
#define NFEAT    164
#define HORIZON  96
#define DMODEL   64
#define DSTATE   16
#define DINNER   128
#define DTRANK   4
#define MLPH     64
#define BATCH    512
#define NSEG     4
#define SEG      84      // timesteps per segment (4*84 = 336)
#define TCK      21      // timesteps per chunk (4 chunks/segment)
#define XCP      132     // padded row stride

// workspace layout (floats)
#define WS_H_ELEMS     (BATCH * NSEG * DINNER * DSTATE)   // 4,194,304
#define WS_DELTA_OFF   WS_H_ELEMS
#define WS_DELTA_ELEMS (BATCH * NSEG * DINNER)            // 262,144
#define WS_XCL_OFF     (WS_DELTA_OFF + WS_DELTA_ELEMS)

__device__ __forceinline__ float fast_rcp(float x) { return __builtin_amdgcn_rcpf(x); }
__device__ __forceinline__ float silu_f(float x) {
    return x * fast_rcp(1.f + __expf(-x));
}
__device__ __forceinline__ float softplus_f(float x) {
    return (x > 15.f) ? x : __logf(1.f + __expf(x));
}

// ================= kernel 1: per-segment conv + x_dbl + partial scan =========
__global__ __launch_bounds__(256, 4) void mamba_part(
    const float* __restrict__ x_raw,   // (512,336)
    const float* __restrict__ embed_W, const float* __restrict__ embed_b,
    const float* __restrict__ in_W,    // (64,256)
    const float* __restrict__ conv_W,  const float* __restrict__ conv_b,
    const float* __restrict__ xproj_W, // (128,36)
    const float* __restrict__ dt_W,    const float* __restrict__ dt_b,
    const float* __restrict__ A_log,
    float* __restrict__ ws_h, float* __restrict__ ws_delta,
    float* __restrict__ ws_xclast)
{
    __shared__ __align__(16) float xrl[96];              // 87 used: segment + 3-halo
    __shared__ __align__(16) float xprojT[20][XCP];
    __shared__ __align__(16) float xc[2][TCK][XCP];      // double-buffered conv out
    __shared__ __align__(16) float Bsh[TCK][DSTATE];
    __shared__ __align__(16) float dtraw[TCK][DTRANK];

    const int tid = threadIdx.x;
    const int bid = blockIdx.x;
    const int b = bid >> 2, s = bid & 3;
    const int t0seg = s * SEG;

    // ---- staging (all threads) ----
    if (tid < 87) {
        int gt = t0seg - 3 + tid;
        xrl[tid] = (gt >= 0) ? x_raw[b*LOOKBACK + gt] : 0.f;
    }
    for (int idx = tid; idx < 20*DINNER; idx += 256) {
        int jj = idx >> 7, d = idx & 127;
        xprojT[jj][d] = xproj_W[d*36 + jj];
    }

    // ---- per-role register setup ----
    // scan lanes: tid 0..127, channel d = tid, ALL 16 states
    float dtw0=0.f, dtw1=0.f, dtw2=0.f, dtw3=0.f, dtb_r=0.f;
    float Areg[16], h[16];
    bool structured = true;
    // conv lanes: tid 128..255, channel ch = tid-128
    float w1=0.f, w0=0.f, cbias=0.f;
    float4 cw = {0.f,0.f,0.f,0.f};

    if (tid < 128) {
        const int d = tid;
        dtw0 = dt_W[0*DINNER + d]; dtw1 = dt_W[1*DINNER + d];
        dtw2 = dt_W[2*DINNER + d]; dtw3 = dt_W[3*DINNER + d];
        dtb_r = dt_b[d];
        #pragma unroll
        for (int i = 0; i < 16; ++i) {
            Areg[i] = -__expf(A_log[d*DSTATE + i]);
            float expect = (float)(i + 1);
            structured = structured && (fabsf(Areg[i] + expect) < 1e-3f * expect);
            h[i] = 0.f;
        }
    } else {
        const int ch = tid - 128;
        float a1 = 0.f, a0 = 0.f;
        for (int dm = 0; dm < DMODEL; ++dm) {
            float w = in_W[dm*(2*DINNER) + ch];
            a1 = fmaf(embed_W[dm], w, a1);
            a0 = fmaf(embed_b[dm], w, a0);
        }
        w1 = a1; w0 = a0;
        cw = *(const float4*)&conv_W[ch*4];
        cbias = conv_b[ch];
    }
    __syncthreads();   // xrl ready for conv

    // ---- conv chunk 0 (conv lanes) ----
    if (tid >= 128) {
        const int ch = tid - 128;
        if (t0seg == 0) {   // zero-pad: skip taps with global t < 0
            #pragma unroll
            for (int tt = 0; tt < TCK; ++tt) {
                float acc = cbias;
                if (tt >= 3) acc = fmaf(fmaf(xrl[tt],   w1, w0), cw.x, acc);
                if (tt >= 2) acc = fmaf(fmaf(xrl[tt+1], w1, w0), cw.y, acc);
                if (tt >= 1) acc = fmaf(fmaf(xrl[tt+2], w1, w0), cw.z, acc);
                acc = fmaf(fmaf(xrl[tt+3], w1, w0), cw.w, acc);
                xc[0][tt][ch] = silu_f(acc);
            }
        } else {
            float e0 = fmaf(xrl[0], w1, w0);
            float e1 = fmaf(xrl[1], w1, w0);
            float e2 = fmaf(xrl[2], w1, w0);
            #pragma unroll
            for (int tt = 0; tt < TCK; ++tt) {
                float e3 = fmaf(xrl[tt+3], w1, w0);
                float acc = cbias + e0*cw.x + e1*cw.y + e2*cw.z + e3*cw.w;
                xc[0][tt][ch] = silu_f(acc);
                e0 = e1; e1 = e2; e2 = e3;
            }
        }
    }
    __syncthreads();

    float dacc = 0.f;

    // ---- main loop: A2 | barrier | scan(c) || conv(c+1) | barrier ----
    for (int c = 0; c < 4; ++c) {
        const int buf = c & 1;
        const float* __restrict__ xcb = &xc[buf][0][0];

        // A2: [21 x 128] @ [128 x 20] -> dtraw(4) + Bsh(16); 210 threads
        if (tid < 210) {
            const int tt = tid / 10;
            const int j0 = (tid - tt*10) * 2;
            const float* p0 = &xprojT[j0][0];
            const float* p1 = &xprojT[j0+1][0];
            const float* xrow = xcb + tt*XCP;
            float a0 = 0.f, a1 = 0.f;
            #pragma unroll 4
            for (int d = 0; d < DINNER; d += 4) {
                float4 xv = *(const float4*)(xrow + d);
                float4 q0 = *(const float4*)(p0 + d);
                float4 q1 = *(const float4*)(p1 + d);
                a0 += xv.x*q0.x + xv.y*q0.y + xv.z*q0.z + xv.w*q0.w;
                a1 += xv.x*q1.x + xv.y*q1.y + xv.z*q1.z + xv.w*q1.w;
            }
            if (j0 < 4) { float2 r = {a0, a1}; *(float2*)&dtraw[tt][j0] = r; }
            else        { float2 r = {a0, a1}; *(float2*)&Bsh[tt][j0-4] = r; }
        }
        __syncthreads();

        if (tid < 128) {
            // -------- scan chunk c: 16 states, no duplication --------
            const int d = tid;
            if (structured) {
                #pragma unroll
                for (int tt = 0; tt < TCK; ++tt) {
                    float4 dr = *(const float4*)&dtraw[tt][0];       // broadcast
                    float dv = fmaf(dr.x, dtw0, fmaf(dr.y, dtw1,
                               fmaf(dr.z, dtw2, fmaf(dr.w, dtw3, dtb_r))));
                    float e  = __expf(dv);
                    float p  = 1.f + e;
                    float r  = fast_rcp(p);                  // exp(-delta)
                    float dl = (dv > 80.f) ? dv : __logf(p); // delta
                    dacc += dl;
                    float ux = dl * xcb[tt*XCP + d];
                    float4 B0 = *(const float4*)&Bsh[tt][0];         // broadcast
                    float4 B1 = *(const float4*)&Bsh[tt][4];
                    float4 B2 = *(const float4*)&Bsh[tt][8];
                    float4 B3 = *(const float4*)&Bsh[tt][12];
                    float r2 = r*r,   r3 = r2*r,  r4  = r2*r2;
                    float r5 = r4*r,  r6 = r4*r2, r7  = r4*r3, r8 = r4*r4;
                    float r9 = r8*r,  r10= r8*r2, r11 = r8*r3, r12= r8*r4;
                    float r13= r8*r5, r14= r8*r6, r15 = r8*r7, r16= r8*r8;
                    h[0]  = fmaf(r,   h[0],  ux*B0.x);
                    h[1]  = fmaf(r2,  h[1],  ux*B0.y);
                    h[2]  = fmaf(r3,  h[2],  ux*B0.z);
                    h[3]  = fmaf(r4,  h[3],  ux*B0.w);
                    h[4]  = fmaf(r5,  h[4],  ux*B1.x);
                    h[5]  = fmaf(r6,  h[5],  ux*B1.y);
                    h[6]  = fmaf(r7,  h[6],  ux*B1.z);
                    h[7]  = fmaf(r8,  h[7],  ux*B1.w);
                    h[8]  = fmaf(r9,  h[8],  ux*B2.x);
                    h[9]  = fmaf(r10, h[9],  ux*B2.y);
                    h[10] = fmaf(r11, h[10], ux*B2.z);
                    h[11] = fmaf(r12, h[11], ux*B2.w);
                    h[12] = fmaf(r13, h[12], ux*B3.x);
                    h[13] = fmaf(r14, h[13], ux*B3.y);
                    h[14] = fmaf(r15, h[14], ux*B3.z);
                    h[15] = fmaf(r16, h[15], ux*B3.w);
                }
            } else {
                #pragma unroll 2
                for (int tt = 0; tt < TCK; ++tt) {
                    float4 dr = *(const float4*)&dtraw[tt][0];
                    float dv = fmaf(dr.x, dtw0, fmaf(dr.y, dtw1,
                               fmaf(dr.z, dtw2, fmaf(dr.w, dtw3, dtb_r))));
                    float dl = softplus_f(dv);
                    dacc += dl;
                    float ux = dl * xcb[tt*XCP + d];
                    const float* Brow = &Bsh[tt][0];
                    #pragma unroll
                    for (int i = 0; i < 16; ++i)
                        h[i] = fmaf(__expf(dl*Areg[i]), h[i], ux*Brow[i]);
                }
            }
        } else if (c < 3) {
            // -------- conv chunk c+1 into other buffer --------
            const int ch = tid - 128;
            const int cb = (c+1)*TCK;
            float* __restrict__ xw = &xc[1-buf][0][0];
            float e0 = fmaf(xrl[cb+0], w1, w0);
            float e1 = fmaf(xrl[cb+1], w1, w0);
            float e2 = fmaf(xrl[cb+2], w1, w0);
            float vlast = 0.f;
            #pragma unroll
            for (int tt = 0; tt < TCK; ++tt) {
                float e3 = fmaf(xrl[cb+tt+3], w1, w0);
                float acc = cbias + e0*cw.x + e1*cw.y + e2*cw.z + e3*cw.w;
                float v = silu_f(acc);
                xw[tt*XCP + ch] = v;
                vlast = v;
                e0 = e1; e1 = e2; e2 = e3;
            }
            if (t0seg + cb + TCK - 1 == LOOKBACK - 1)   // block-uniform
                ws_xclast[b*DINNER + ch] = vlast;
        }
        __syncthreads();
    }

    // ---- write partials ----
    if (tid < 128) {
        const int d = tid;
        float4* hp = (float4*)&ws_h[bid*(DINNER*DSTATE) + d*DSTATE];
        hp[0] = make_float4(h[0],  h[1],  h[2],  h[3]);
        hp[1] = make_float4(h[4],  h[5],  h[6],  h[7]);
        hp[2] = make_float4(h[8],  h[9],  h[10], h[11]);
        hp[3] = make_float4(h[12], h[13], h[14], h[15]);
        ws_delta[bid*DINNER + d] = dacc;
    }
}

// ================= kernel 2: combine segments + epilogue + MLP + head ========
__global__ __launch_bounds__(256, 2) void mamba_combine(
    const float* __restrict__ x_raw, const float* __restrict__ x_features,
    const float* __restrict__ embed_W, const float* __restrict__ embed_b,
    const float* __restrict__ in_W, const float* __restrict__ xproj_W,
    const float* __restrict__ A_log, const float* __restrict__ Dvec,
    const float* __restrict__ out_W,
    const float* __restrict__ mlp_W1, const float* __restrict__ mlp_b1,
    const float* __restrict__ mlp_W2, const float* __restrict__ mlp_b2,
    const float* __restrict__ head_W, const float* __restrict__ head_b,
    const float* __restrict__ ws_h, const float* __restrict__ ws_delta,
    const float* __restrict__ ws_xclast,
    float* __restrict__ out)
{
    __shared__ float xcl[DINNER], zs[DINNER], Cl[DSTATE], yv[DINNER];
    __shared__ float hfin[96], mlph[MLPH];

    const int tid = threadIdx.x;
    const int b   = blockIdx.x;
    const int dB  = tid >> 1;
    const int n0  = (tid & 1) * 8;

    // combine partial h:  h = sum_s exp(A * S_s) * h_s,  S_s = suffix delta sum
    float Areg[8];
    #pragma unroll
    for (int i = 0; i < 8; ++i) Areg[i] = -__expf(A_log[dB*DSTATE + n0 + i]);
    float d1 = ws_delta[(b*4+1)*DINNER + dB];
    float d2 = ws_delta[(b*4+2)*DINNER + dB];
    float d3 = ws_delta[(b*4+3)*DINNER + dB];
    float Ss[3] = {d1+d2+d3, d2+d3, d3};
    float hc[8];
    {   const float4* hp = (const float4*)&ws_h[(b*4+3)*(DINNER*DSTATE) + dB*DSTATE + n0];
        float4 a = hp[0], c = hp[1];
        hc[0]=a.x; hc[1]=a.y; hc[2]=a.z; hc[3]=a.w;
        hc[4]=c.x; hc[5]=c.y; hc[6]=c.z; hc[7]=c.w;
    }
    #pragma unroll
    for (int s = 0; s < 3; ++s) {
        const float4* hp = (const float4*)&ws_h[(b*4+s)*(DINNER*DSTATE) + dB*DSTATE + n0];
        float4 a = hp[0], c = hp[1];
        float hs[8] = {a.x,a.y,a.z,a.w,c.x,c.y,c.z,c.w};
        float S = Ss[s];
        #pragma unroll
        for (int i = 0; i < 8; ++i) hc[i] = fmaf(__expf(Areg[i]*S), hs[i], hc[i]);
    }

    // phase 1: xc_last, z-gate, MLP stage 1
    if (tid < DINNER) {
        xcl[tid] = ws_xclast[b*DINNER + tid];
        float a1 = 0.f, a0 = 0.f;
        for (int dm = 0; dm < DMODEL; ++dm) {
            float w = in_W[dm*(2*DINNER) + DINNER + tid];   // z-half cols
            a1 = fmaf(embed_W[dm], w, a1);
            a0 = fmaf(embed_b[dm], w, a0);
        }
        float zv = fmaf(x_raw[b*LOOKBACK + LOOKBACK-1], a1, a0);
        zs[tid] = silu_f(zv);
    } else if (tid < 192) {
        int j = tid - 128;
        float acc = mlp_b1[j];
        const float* xf = x_features + b*NFEAT;
        for (int f = 0; f < NFEAT; ++f) acc = fmaf(xf[f], mlp_W1[f*MLPH + j], acc);
        mlph[j] = fmaxf(acc, 0.f);
    }
    __syncthreads();

    // phase 2: C at t=335, MLP stage 2
    if (tid < DSTATE) {
        float acc = 0.f;
        for (int d = 0; d < DINNER; ++d) acc = fmaf(xcl[d], xproj_W[d*36 + 20 + tid], acc);
        Cl[tid] = acc;
    } else if (tid >= 32 && tid < 64) {
        int j = tid - 32;
        float acc = mlp_b2[j];
        for (int k = 0; k < MLPH; ++k) acc = fmaf(mlph[k], mlp_W2[k*32 + j], acc);
        hfin[64 + j] = acc;
    }
    __syncthreads();

    // phase 3: y = (h·C + xc_last*D) * silu(z)
    {
        float part = 0.f;
        #pragma unroll
        for (int i = 0; i < 8; ++i) part = fmaf(hc[i], Cl[n0 + i], part);
        float other = __shfl_xor(part, 1);
        if ((tid & 1) == 0) {
            float y = part + other + xcl[dB]*Dvec[dB];
            yv[dB] = y * zs[dB];
        }
    }
    __syncthreads();

    // phase 4: out projection
    if (tid < DMODEL) {
        float acc = 0.f;
        for (int d = 0; d < DINNER; ++d) acc = fmaf(yv[d], out_W[d*DMODEL + tid], acc);
        hfin[tid] = acc;
    }
    __syncthreads();

    // phase 5: head
    if (tid < HORIZON) {
        float acc = head_b[tid];
        for (int i = 0; i < 96; ++i) acc = fmaf(hfin[i], head_W[i*HORIZON + tid], acc);
        out[b*HORIZON + tid] = acc;
    }
}

extern "C" void kernel_launch(void* const* d_in, const int* in_sizes, int n_in,
                              void* d_out, int out_size, void* d_ws, size_t ws_size,
                              hipStream_t stream) {
    (void)in_sizes; (void)n_in; (void)out_size; (void)ws_size;
    float* ws        = (float*)d_ws;
    float* ws_h      = ws;
    float* ws_delta  = ws + WS_DELTA_OFF;
    float* ws_xclast = ws + WS_XCL_OFF;

    mamba_part<<<BATCH*NSEG, 256, 0, stream>>>(
        (const float*)d_in[0],  (const float*)d_in[2],  (const float*)d_in[3],
        (const float*)d_in[4],  (const float*)d_in[5],  (const float*)d_in[6],
        (const float*)d_in[7],  (const float*)d_in[8],  (const float*)d_in[9],
        (const float*)d_in[10],
        ws_h, ws_delta, ws_xclast);

    mamba_combine<<<BATCH, 256, 0, stream>>>(
        (const float*)d_in[0],  (const float*)d_in[1],  (const float*)d_in[2],
        (const float*)d_in[3],  (const float*)d_in[4],  (const float*)d_in[7],
        (const float*)d_in[10], (const float*)d_in[11], (const float*)d_in[12],
        (const float*)d_in[13], (const float*)d_in[14], (const float*)d_in[15],
        (const float*)d_in[16], (const float*)d_in[17], (const float*)d_in[18],
        ws_h, ws_delta, ws_xclast,
        (float*)d_out);
}

// Round 6
// 227.406 us; speedup vs baseline: 1.9765x; 1.9765x over previous
//
#include <hip/hip_runtime.h>
#include <math.h>

#define LOOKBACK 336
#define NFEAT    164
#define HORIZON  96
#define DMODEL   64
#define DSTATE   16
#define DINNER   128
#define DTRANK   4
#define MLPH     64
#define BATCH    512
#define NSEG     4
#define SEG      84      // timesteps per segment (4*84 = 336)
#define TCK      21      // timesteps per chunk (4 chunks/segment)
#define XCP      132     // padded row stride

// workspace layout (floats)
#define WS_H_ELEMS     (BATCH * NSEG * DINNER * DSTATE)   // 4,194,304
#define WS_DELTA_OFF   WS_H_ELEMS
#define WS_DELTA_ELEMS (BATCH * NSEG * DINNER)            // 262,144
#define WS_XCL_OFF     (WS_DELTA_OFF + WS_DELTA_ELEMS)

__device__ __forceinline__ float fast_rcp(float x) { return __builtin_amdgcn_rcpf(x); }
__device__ __forceinline__ float silu_f(float x) {
    return x * fast_rcp(1.f + __expf(-x));
}
__device__ __forceinline__ float softplus_f(float x) {
    return (x > 15.f) ? x : __logf(1.f + __expf(x));
}

// ================= kernel 1: per-segment conv + x_dbl + partial scan =========
// NOTE: __launch_bounds__(256,4) capped VGPRs at 64 here (R5) and spilled
// h[16] to scratch -> 1.3 GB/dispatch of spill traffic. Use (256,2): LDS
// (35 KB -> 4 blocks/CU) is the intended occupancy limiter, not VGPRs.
__global__ __launch_bounds__(256, 2) void mamba_part(
    const float* __restrict__ x_raw,   // (512,336)
    const float* __restrict__ embed_W, const float* __restrict__ embed_b,
    const float* __restrict__ in_W,    // (64,256)
    const float* __restrict__ conv_W,  const float* __restrict__ conv_b,
    const float* __restrict__ xproj_W, // (128,36)
    const float* __restrict__ dt_W,    const float* __restrict__ dt_b,
    const float* __restrict__ A_log,
    float* __restrict__ ws_h, float* __restrict__ ws_delta,
    float* __restrict__ ws_xclast)
{
    __shared__ __align__(16) float xrl[96];              // 87 used: segment + 3-halo
    __shared__ __align__(16) float xprojT[20][XCP];
    __shared__ __align__(16) float xc[2][TCK][XCP];      // double-buffered conv out
    __shared__ __align__(16) float Bsh[TCK][DSTATE];
    __shared__ __align__(16) float dtraw[TCK][DTRANK];

    const int tid = threadIdx.x;
    const int bid = blockIdx.x;
    const int b = bid >> 2, s = bid & 3;
    const int t0seg = s * SEG;

    // ---- staging (all threads) ----
    if (tid < 87) {
        int gt = t0seg - 3 + tid;
        xrl[tid] = (gt >= 0) ? x_raw[b*LOOKBACK + gt] : 0.f;
    }
    for (int idx = tid; idx < 20*DINNER; idx += 256) {
        int jj = idx >> 7, d = idx & 127;
        xprojT[jj][d] = xproj_W[d*36 + jj];
    }

    // ---- per-role register setup ----
    // scan lanes: tid 0..127, channel d = tid, ALL 16 states
    float dtw0=0.f, dtw1=0.f, dtw2=0.f, dtw3=0.f, dtb_r=0.f;
    float h[16];
    bool structured = true;
    // conv lanes: tid 128..255, channel ch = tid-128
    float w1=0.f, w0=0.f, cbias=0.f;
    float4 cw = {0.f,0.f,0.f,0.f};

    if (tid < 128) {
        const int d = tid;
        dtw0 = dt_W[0*DINNER + d]; dtw1 = dt_W[1*DINNER + d];
        dtw2 = dt_W[2*DINNER + d]; dtw3 = dt_W[3*DINNER + d];
        dtb_r = dt_b[d];
        // structure check only — no persistent Areg (register pressure!)
        #pragma unroll
        for (int i = 0; i < 16; ++i) {
            float a = __expf(A_log[d*DSTATE + i]);
            float expect = (float)(i + 1);
            structured = structured && (fabsf(a - expect) < 1e-3f * expect);
            h[i] = 0.f;
        }
    } else {
        const int ch = tid - 128;
        float a1 = 0.f, a0 = 0.f;
        for (int dm = 0; dm < DMODEL; ++dm) {
            float w = in_W[dm*(2*DINNER) + ch];
            a1 = fmaf(embed_W[dm], w, a1);
            a0 = fmaf(embed_b[dm], w, a0);
        }
        w1 = a1; w0 = a0;
        cw = *(const float4*)&conv_W[ch*4];
        cbias = conv_b[ch];
    }
    __syncthreads();   // xrl ready for conv

    // ---- conv chunk 0 (conv lanes) ----
    if (tid >= 128) {
        const int ch = tid - 128;
        if (t0seg == 0) {   // zero-pad: skip taps with global t < 0
            #pragma unroll
            for (int tt = 0; tt < TCK; ++tt) {
                float acc = cbias;
                if (tt >= 3) acc = fmaf(fmaf(xrl[tt],   w1, w0), cw.x, acc);
                if (tt >= 2) acc = fmaf(fmaf(xrl[tt+1], w1, w0), cw.y, acc);
                if (tt >= 1) acc = fmaf(fmaf(xrl[tt+2], w1, w0), cw.z, acc);
                acc = fmaf(fmaf(xrl[tt+3], w1, w0), cw.w, acc);
                xc[0][tt][ch] = silu_f(acc);
            }
        } else {
            float e0 = fmaf(xrl[0], w1, w0);
            float e1 = fmaf(xrl[1], w1, w0);
            float e2 = fmaf(xrl[2], w1, w0);
            #pragma unroll
            for (int tt = 0; tt < TCK; ++tt) {
                float e3 = fmaf(xrl[tt+3], w1, w0);
                float acc = cbias + e0*cw.x + e1*cw.y + e2*cw.z + e3*cw.w;
                xc[0][tt][ch] = silu_f(acc);
                e0 = e1; e1 = e2; e2 = e3;
            }
        }
    }
    __syncthreads();

    float dacc = 0.f;

    // ---- main loop: A2 | barrier | scan(c) || conv(c+1) | barrier ----
    for (int c = 0; c < 4; ++c) {
        const int buf = c & 1;
        const float* __restrict__ xcb = &xc[buf][0][0];

        // A2: [21 x 128] @ [128 x 20] -> dtraw(4) + Bsh(16); 210 threads
        if (tid < 210) {
            const int tt = tid / 10;
            const int j0 = (tid - tt*10) * 2;
            const float* p0 = &xprojT[j0][0];
            const float* p1 = &xprojT[j0+1][0];
            const float* xrow = xcb + tt*XCP;
            float a0 = 0.f, a1 = 0.f;
            #pragma unroll 4
            for (int d = 0; d < DINNER; d += 4) {
                float4 xv = *(const float4*)(xrow + d);
                float4 q0 = *(const float4*)(p0 + d);
                float4 q1 = *(const float4*)(p1 + d);
                a0 += xv.x*q0.x + xv.y*q0.y + xv.z*q0.z + xv.w*q0.w;
                a1 += xv.x*q1.x + xv.y*q1.y + xv.z*q1.z + xv.w*q1.w;
            }
            if (j0 < 4) { float2 r = {a0, a1}; *(float2*)&dtraw[tt][j0] = r; }
            else        { float2 r = {a0, a1}; *(float2*)&Bsh[tt][j0-4] = r; }
        }
        __syncthreads();

        if (tid < 128) {
            // -------- scan chunk c: 16 states, no duplication --------
            const int d = tid;
            if (__builtin_expect(structured, 1)) {
                #pragma unroll
                for (int tt = 0; tt < TCK; ++tt) {
                    float4 dr = *(const float4*)&dtraw[tt][0];       // broadcast
                    float dv = fmaf(dr.x, dtw0, fmaf(dr.y, dtw1,
                               fmaf(dr.z, dtw2, fmaf(dr.w, dtw3, dtb_r))));
                    float e  = __expf(dv);
                    float p  = 1.f + e;
                    float r  = fast_rcp(p);                  // exp(-delta)
                    float dl = (dv > 80.f) ? dv : __logf(p); // delta
                    dacc += dl;
                    float ux = dl * xcb[tt*XCP + d];
                    float4 B0 = *(const float4*)&Bsh[tt][0];         // broadcast
                    float4 B1 = *(const float4*)&Bsh[tt][4];
                    float4 B2 = *(const float4*)&Bsh[tt][8];
                    float4 B3 = *(const float4*)&Bsh[tt][12];
                    float r2 = r*r,   r3 = r2*r,  r4  = r2*r2;
                    float r5 = r4*r,  r6 = r4*r2, r7  = r4*r3, r8 = r4*r4;
                    float r9 = r8*r,  r10= r8*r2, r11 = r8*r3, r12= r8*r4;
                    float r13= r8*r5, r14= r8*r6, r15 = r8*r7, r16= r8*r8;
                    h[0]  = fmaf(r,   h[0],  ux*B0.x);
                    h[1]  = fmaf(r2,  h[1],  ux*B0.y);
                    h[2]  = fmaf(r3,  h[2],  ux*B0.z);
                    h[3]  = fmaf(r4,  h[3],  ux*B0.w);
                    h[4]  = fmaf(r5,  h[4],  ux*B1.x);
                    h[5]  = fmaf(r6,  h[5],  ux*B1.y);
                    h[6]  = fmaf(r7,  h[6],  ux*B1.z);
                    h[7]  = fmaf(r8,  h[7],  ux*B1.w);
                    h[8]  = fmaf(r9,  h[8],  ux*B2.x);
                    h[9]  = fmaf(r10, h[9],  ux*B2.y);
                    h[10] = fmaf(r11, h[10], ux*B2.z);
                    h[11] = fmaf(r12, h[11], ux*B2.w);
                    h[12] = fmaf(r13, h[12], ux*B3.x);
                    h[13] = fmaf(r14, h[13], ux*B3.y);
                    h[14] = fmaf(r15, h[14], ux*B3.z);
                    h[15] = fmaf(r16, h[15], ux*B3.w);
                }
            } else {
                // slow fallback (never taken with reference inputs): reload
                // A_log from global per step to keep zero persistent regs
                const float* Arow = A_log + d*DSTATE;
                for (int tt = 0; tt < TCK; ++tt) {
                    float4 dr = *(const float4*)&dtraw[tt][0];
                    float dv = fmaf(dr.x, dtw0, fmaf(dr.y, dtw1,
                               fmaf(dr.z, dtw2, fmaf(dr.w, dtw3, dtb_r))));
                    float dl = softplus_f(dv);
                    dacc += dl;
                    float ux = dl * xcb[tt*XCP + d];
                    const float* Brow = &Bsh[tt][0];
                    for (int i = 0; i < 16; ++i)
                        h[i] = fmaf(__expf(-__expf(Arow[i])*dl), h[i], ux*Brow[i]);
                }
            }
        } else if (c < 3) {
            // -------- conv chunk c+1 into other buffer --------
            const int ch = tid - 128;
            const int cb = (c+1)*TCK;
            float* __restrict__ xw = &xc[1-buf][0][0];
            float e0 = fmaf(xrl[cb+0], w1, w0);
            float e1 = fmaf(xrl[cb+1], w1, w0);
            float e2 = fmaf(xrl[cb+2], w1, w0);
            float vlast = 0.f;
            #pragma unroll
            for (int tt = 0; tt < TCK; ++tt) {
                float e3 = fmaf(xrl[cb+tt+3], w1, w0);
                float acc = cbias + e0*cw.x + e1*cw.y + e2*cw.z + e3*cw.w;
                float v = silu_f(acc);
                xw[tt*XCP + ch] = v;
                vlast = v;
                e0 = e1; e1 = e2; e2 = e3;
            }
            if (t0seg + cb + TCK - 1 == LOOKBACK - 1)   // block-uniform
                ws_xclast[b*DINNER + ch] = vlast;
        }
        __syncthreads();
    }

    // ---- write partials ----
    if (tid < 128) {
        const int d = tid;
        float4* hp = (float4*)&ws_h[bid*(DINNER*DSTATE) + d*DSTATE];
        hp[0] = make_float4(h[0],  h[1],  h[2],  h[3]);
        hp[1] = make_float4(h[4],  h[5],  h[6],  h[7]);
        hp[2] = make_float4(h[8],  h[9],  h[10], h[11]);
        hp[3] = make_float4(h[12], h[13], h[14], h[15]);
        ws_delta[bid*DINNER + d] = dacc;
    }
}

// ================= kernel 2: combine segments + epilogue + MLP + head ========
__global__ __launch_bounds__(256, 2) void mamba_combine(
    const float* __restrict__ x_raw, const float* __restrict__ x_features,
    const float* __restrict__ embed_W, const float* __restrict__ embed_b,
    const float* __restrict__ in_W, const float* __restrict__ xproj_W,
    const float* __restrict__ A_log, const float* __restrict__ Dvec,
    const float* __restrict__ out_W,
    const float* __restrict__ mlp_W1, const float* __restrict__ mlp_b1,
    const float* __restrict__ mlp_W2, const float* __restrict__ mlp_b2,
    const float* __restrict__ head_W, const float* __restrict__ head_b,
    const float* __restrict__ ws_h, const float* __restrict__ ws_delta,
    const float* __restrict__ ws_xclast,
    float* __restrict__ out)
{
    __shared__ float xcl[DINNER], zs[DINNER], Cl[DSTATE], yv[DINNER];
    __shared__ float hfin[96], mlph[MLPH];

    const int tid = threadIdx.x;
    const int b   = blockIdx.x;
    const int dB  = tid >> 1;
    const int n0  = (tid & 1) * 8;

    // combine partial h:  h = sum_s exp(A * S_s) * h_s,  S_s = suffix delta sum
    float Areg[8];
    #pragma unroll
    for (int i = 0; i < 8; ++i) Areg[i] = -__expf(A_log[dB*DSTATE + n0 + i]);
    float d1 = ws_delta[(b*4+1)*DINNER + dB];
    float d2 = ws_delta[(b*4+2)*DINNER + dB];
    float d3 = ws_delta[(b*4+3)*DINNER + dB];
    float Ss[3] = {d1+d2+d3, d2+d3, d3};
    float hc[8];
    {   const float4* hp = (const float4*)&ws_h[(b*4+3)*(DINNER*DSTATE) + dB*DSTATE + n0];
        float4 a = hp[0], c = hp[1];
        hc[0]=a.x; hc[1]=a.y; hc[2]=a.z; hc[3]=a.w;
        hc[4]=c.x; hc[5]=c.y; hc[6]=c.z; hc[7]=c.w;
    }
    #pragma unroll
    for (int s = 0; s < 3; ++s) {
        const float4* hp = (const float4*)&ws_h[(b*4+s)*(DINNER*DSTATE) + dB*DSTATE + n0];
        float4 a = hp[0], c = hp[1];
        float hs[8] = {a.x,a.y,a.z,a.w,c.x,c.y,c.z,c.w};
        float S = Ss[s];
        #pragma unroll
        for (int i = 0; i < 8; ++i) hc[i] = fmaf(__expf(Areg[i]*S), hs[i], hc[i]);
    }

    // phase 1: xc_last, z-gate, MLP stage 1
    if (tid < DINNER) {
        xcl[tid] = ws_xclast[b*DINNER + tid];
        float a1 = 0.f, a0 = 0.f;
        for (int dm = 0; dm < DMODEL; ++dm) {
            float w = in_W[dm*(2*DINNER) + DINNER + tid];   // z-half cols
            a1 = fmaf(embed_W[dm], w, a1);
            a0 = fmaf(embed_b[dm], w, a0);
        }
        float zv = fmaf(x_raw[b*LOOKBACK + LOOKBACK-1], a1, a0);
        zs[tid] = silu_f(zv);
    } else if (tid < 192) {
        int j = tid - 128;
        float acc = mlp_b1[j];
        const float* xf = x_features + b*NFEAT;
        for (int f = 0; f < NFEAT; ++f) acc = fmaf(xf[f], mlp_W1[f*MLPH + j], acc);
        mlph[j] = fmaxf(acc, 0.f);
    }
    __syncthreads();

    // phase 2: C at t=335, MLP stage 2
    if (tid < DSTATE) {
        float acc = 0.f;
        for (int d = 0; d < DINNER; ++d) acc = fmaf(xcl[d], xproj_W[d*36 + 20 + tid], acc);
        Cl[tid] = acc;
    } else if (tid >= 32 && tid < 64) {
        int j = tid - 32;
        float acc = mlp_b2[j];
        for (int k = 0; k < MLPH; ++k) acc = fmaf(mlph[k], mlp_W2[k*32 + j], acc);
        hfin[64 + j] = acc;
    }
    __syncthreads();

    // phase 3: y = (h·C + xc_last*D) * silu(z)
    {
        float part = 0.f;
        #pragma unroll
        for (int i = 0; i < 8; ++i) part = fmaf(hc[i], Cl[n0 + i], part);
        float other = __shfl_xor(part, 1);
        if ((tid & 1) == 0) {
            float y = part + other + xcl[dB]*Dvec[dB];
            yv[dB] = y * zs[dB];
        }
    }
    __syncthreads();

    // phase 4: out projection
    if (tid < DMODEL) {
        float acc = 0.f;
        for (int d = 0; d < DINNER; ++d) acc = fmaf(yv[d], out_W[d*DMODEL + tid], acc);
        hfin[tid] = acc;
    }
    __syncthreads();

    // phase 5: head
    if (tid < HORIZON) {
        float acc = head_b[tid];
        for (int i = 0; i < 96; ++i) acc = fmaf(hfin[i], head_W[i*HORIZON + tid], acc);
        out[b*HORIZON + tid] = acc;
    }
}

extern "C" void kernel_launch(void* const* d_in, const int* in_sizes, int n_in,
                              void* d_out, int out_size, void* d_ws, size_t ws_size,
                              hipStream_t stream) {
    (void)in_sizes; (void)n_in; (void)out_size; (void)ws_size;
    float* ws        = (float*)d_ws;
    float* ws_h      = ws;
    float* ws_delta  = ws + WS_DELTA_OFF;
    float* ws_xclast = ws + WS_XCL_OFF;

    mamba_part<<<BATCH*NSEG, 256, 0, stream>>>(
        (const float*)d_in[0],  (const float*)d_in[2],  (const float*)d_in[3],
        (const float*)d_in[4],  (const float*)d_in[5],  (const float*)d_in[6],
        (const float*)d_in[7],  (const float*)d_in[8],  (const float*)d_in[9],
        (const float*)d_in[10],
        ws_h, ws_delta, ws_xclast);

    mamba_combine<<<BATCH, 256, 0, stream>>>(
        (const float*)d_in[0],  (const float*)d_in[1],  (const float*)d_in[2],
        (const float*)d_in[3],  (const float*)d_in[4],  (const float*)d_in[7],
        (const float*)d_in[10], (const float*)d_in[11], (const float*)d_in[12],
        (const float*)d_in[13], (const float*)d_in[14], (const float*)d_in[15],
        (const float*)d_in[16], (const float*)d_in[17], (const float*)d_in[18],
        ws_h, ws_delta, ws_xclast,
        (float*)d_out);
}

// Round 7
// 219.408 us; speedup vs baseline: 2.0486x; 1.0365x over previous
//
#include <hip/hip_runtime.h>
#include <math.h>

#define LOOKBACK 336
#define NFEAT    164
#define HORIZON  96
#define DMODEL   64
#define DSTATE   16
#define DINNER   128
#define MLPH     64
#define BATCH    512
#define XCP      132

typedef float v2f __attribute__((ext_vector_type(2)));

__device__ __forceinline__ float fast_rcp(float x) { return __builtin_amdgcn_rcpf(x); }
__device__ __forceinline__ float silu_f(float x) {
    return x * fast_rcp(1.f + __expf(-x));
}

// one scan timestep; HI selects states 8..15 (extra r^8 scale), wave-uniform
#define SCAN_STEP(HI)                                                          \
    {                                                                          \
        float4 dr = *(const float4*)&dtraw[tt][0];                             \
        float dv = fmaf(dr.x, dtw0, fmaf(dr.y, dtw1,                           \
                   fmaf(dr.z, dtw2, fmaf(dr.w, dtw3, dtb_r))));                \
        float e  = __expf(dv);                                                 \
        float p  = 1.f + e;                                                    \
        float r  = fast_rcp(p);                                                \
        float dl = (dv > 80.f) ? dv : __logf(p);                               \
        dacc += dl;                                                            \
        float ux = dl * xc[tt*XCP + ch];                                       \
        float4 Bq0 = *(const float4*)&Bsh[tt][(HI) ? 8 : 0];                   \
        float4 Bq1 = *(const float4*)&Bsh[tt][(HI) ? 12 : 4];                  \
        float r2 = r*r;                                                        \
        v2f rr2 = {r2, r2};                                                    \
        v2f p01 = {r, r2};                                                     \
        v2f p23 = p01*rr2;                                                     \
        v2f p45 = p23*rr2;                                                     \
        v2f p67 = p45*rr2;                                                     \
        if (HI) { float r8 = p67.y; v2f r8v = {r8, r8};                        \
                  p01 *= r8v; p23 *= r8v; p45 *= r8v; p67 *= r8v; }            \
        v2f uxv = {ux, ux};                                                    \
        v2f b01 = {Bq0.x, Bq0.y}, b23 = {Bq0.z, Bq0.w};                        \
        v2f b45 = {Bq1.x, Bq1.y}, b67 = {Bq1.z, Bq1.w};                        \
        h01 = __builtin_elementwise_fma(p01, h01, uxv*b01);                    \
        h23 = __builtin_elementwise_fma(p23, h23, uxv*b23);                    \
        h45 = __builtin_elementwise_fma(p45, h45, uxv*b45);                    \
        h67 = __builtin_elementwise_fma(p67, h67, uxv*b67);                    \
    }

// ============ kernel 1: per-segment conv + x_dbl + partial scan =============
template<int NSEG>
__global__ __launch_bounds__(256, 3) void mamba_part(
    const float* __restrict__ x_raw,   const float* __restrict__ embed_W,
    const float* __restrict__ embed_b, const float* __restrict__ in_W,
    const float* __restrict__ conv_W,  const float* __restrict__ conv_b,
    const float* __restrict__ xproj_W, const float* __restrict__ dt_W,
    const float* __restrict__ dt_b,    const float* __restrict__ A_log,
    float* __restrict__ ws_h, float* __restrict__ ws_delta,
    float* __restrict__ ws_xclast)
{
    constexpr int SEG = LOOKBACK / NSEG;
    constexpr int T1  = (SEG + 1) / 2;
    __shared__ __align__(16) float xrl[SEG + 5];
    __shared__ __align__(16) float w1x[DINNER], w0x[DINNER];
    __shared__ __align__(16) float xprojT[20*XCP];
    __shared__ __align__(16) float xc[SEG*XCP];
    __shared__ __align__(16) float Bsh[SEG][DSTATE];
    __shared__ __align__(16) float dtraw[SEG][4];

    const int tid = threadIdx.x;
    const int bid = blockIdx.x;
    const int b = bid / NSEG, s = bid % NSEG;

    // ---- staging ----
    if (tid < SEG + 3) {
        int gt = s*SEG - 3 + tid;
        xrl[tid] = (gt >= 0) ? x_raw[b*LOOKBACK + gt] : 0.f;
    }
    if (tid < 128) {          // embed folded through in_W (x-half): w1
        float a = 0.f;
        for (int dm = 0; dm < DMODEL; ++dm)
            a = fmaf(embed_W[dm], in_W[dm*(2*DINNER) + tid], a);
        w1x[tid] = a;
    } else {                  // w0
        int c2 = tid - 128;
        float a = 0.f;
        for (int dm = 0; dm < DMODEL; ++dm)
            a = fmaf(embed_b[dm], in_W[dm*(2*DINNER) + c2], a);
        w0x[c2] = a;
    }
    for (int idx = tid; idx < 20*DINNER; idx += 256) {
        int jj = idx >> 7, d = idx & 127;
        xprojT[jj*XCP + d] = xproj_W[d*36 + jj];
    }

    // ---- per-thread channel params (half = wave-uniform state split) ----
    const int half = tid >> 7;
    const int ch   = tid & 127;
    const float4 cw = *(const float4*)&conv_W[ch*4];
    const float  cb = conv_b[ch];
    const float dtw0 = dt_W[ch],        dtw1 = dt_W[128 + ch],
                dtw2 = dt_W[256 + ch],  dtw3 = dt_W[384 + ch];
    const float dtb_r = dt_b[ch];
    bool structured = true;
    #pragma unroll
    for (int i = 0; i < 8; ++i) {
        float a = __expf(A_log[ch*DSTATE + half*8 + i]);
        float expect = (float)(half*8 + i + 1);
        structured = structured && (fabsf(a - expect) < 1e-3f * expect);
    }
    __syncthreads();

    // ---- conv+silu: half 0 does tt 0..T1-1, half 1 does T1..SEG-1 ----
    {
        const float w1 = w1x[ch], w0 = w0x[ch];
        if (s == 0 && half == 0) {    // zero-padded taps at sequence start
            for (int tt = 0; tt < T1; ++tt) {
                float acc = cb;
                if (tt >= 3) acc = fmaf(fmaf(xrl[tt],   w1, w0), cw.x, acc);
                if (tt >= 2) acc = fmaf(fmaf(xrl[tt+1], w1, w0), cw.y, acc);
                if (tt >= 1) acc = fmaf(fmaf(xrl[tt+2], w1, w0), cw.z, acc);
                acc = fmaf(fmaf(xrl[tt+3], w1, w0), cw.w, acc);
                xc[tt*XCP + ch] = silu_f(acc);
            }
        } else {
            const int tb = half ? T1 : 0;
            const int te = half ? SEG : T1;
            float e0 = fmaf(xrl[tb],   w1, w0);
            float e1 = fmaf(xrl[tb+1], w1, w0);
            float e2 = fmaf(xrl[tb+2], w1, w0);
            float v = 0.f;
            for (int tt = tb; tt < te; ++tt) {
                float e3 = fmaf(xrl[tt+3], w1, w0);
                float acc = cb + e0*cw.x + e1*cw.y + e2*cw.z + e3*cw.w;
                v = silu_f(acc);
                xc[tt*XCP + ch] = v;
                e0 = e1; e1 = e2; e2 = e3;
            }
            if (half && s == NSEG-1) ws_xclast[b*DINNER + ch] = v;  // t=335
        }
    }
    __syncthreads();

    // ---- A2: [SEG x 128] @ [128 x 20] -> dtraw(4) + Bsh(16), packed fma ----
    for (int task = tid; task < SEG*10; task += 256) {
        const int tt = task / 10;
        const int j0 = (task - tt*10) * 2;
        const float* p0   = &xprojT[j0*XCP];
        const float* p1   = &xprojT[(j0+1)*XCP];
        const float* xrow = &xc[tt*XCP];
        v2f a0 = {0.f, 0.f}, a1 = {0.f, 0.f};
        #pragma unroll 8
        for (int d = 0; d < DINNER; d += 4) {
            float4 xv = *(const float4*)(xrow + d);
            float4 q0 = *(const float4*)(p0 + d);
            float4 q1 = *(const float4*)(p1 + d);
            v2f xlo = {xv.x, xv.y}, xhi = {xv.z, xv.w};
            v2f q0l = {q0.x, q0.y}, q0h = {q0.z, q0.w};
            v2f q1l = {q1.x, q1.y}, q1h = {q1.z, q1.w};
            a0 = __builtin_elementwise_fma(xlo, q0l, a0);
            a0 = __builtin_elementwise_fma(xhi, q0h, a0);
            a1 = __builtin_elementwise_fma(xlo, q1l, a1);
            a1 = __builtin_elementwise_fma(xhi, q1h, a1);
        }
        float r0 = a0.x + a0.y, r1 = a1.x + a1.y;
        if (j0 < 4) *(float2*)&dtraw[tt][j0] = make_float2(r0, r1);
        else        *(float2*)&Bsh[tt][j0-4] = make_float2(r0, r1);
    }
    __syncthreads();

    // ---- scan: 2 lanes/channel, 8 states each, wave-uniform half ----
    float dacc = 0.f;
    v2f h01 = {0,0}, h23 = {0,0}, h45 = {0,0}, h67 = {0,0};
    if (__builtin_expect(structured, 1)) {
        if (half == 0) {
            #pragma unroll
            for (int tt = 0; tt < SEG; ++tt) SCAN_STEP(false)
        } else {
            #pragma unroll
            for (int tt = 0; tt < SEG; ++tt) SCAN_STEP(true)
        }
    } else {
        // generic fallback (not taken with reference inputs)
        const float* Arow = A_log + ch*DSTATE + half*8;
        for (int tt = 0; tt < SEG; ++tt) {
            float4 dr = *(const float4*)&dtraw[tt][0];
            float dv = fmaf(dr.x, dtw0, fmaf(dr.y, dtw1,
                       fmaf(dr.z, dtw2, fmaf(dr.w, dtw3, dtb_r))));
            float e  = __expf(dv);
            float dl = (dv > 15.f) ? dv : __logf(1.f + e);
            dacc += dl;
            float ux = dl * xc[tt*XCP + ch];
            const float* Brow = &Bsh[tt][half*8];
            float hv[8] = {h01.x,h01.y,h23.x,h23.y,h45.x,h45.y,h67.x,h67.y};
            for (int i = 0; i < 8; ++i)
                hv[i] = fmaf(__expf(-__expf(Arow[i])*dl), hv[i], ux*Brow[i]);
            h01 = (v2f){hv[0],hv[1]}; h23 = (v2f){hv[2],hv[3]};
            h45 = (v2f){hv[4],hv[5]}; h67 = (v2f){hv[6],hv[7]};
        }
    }

    // ---- write partials ----
    {
        float4 o0 = {h01.x, h01.y, h23.x, h23.y};
        float4 o1 = {h45.x, h45.y, h67.x, h67.y};
        float4* hp = (float4*)&ws_h[(size_t)bid*(DINNER*DSTATE) + ch*DSTATE + half*8];
        hp[0] = o0; hp[1] = o1;
    }
    if (half == 0) ws_delta[bid*DINNER + ch] = dacc;
}

// ============ kernel 2: combine segments + epilogue + MLP + head ============
template<int NSEG>
__global__ __launch_bounds__(256, 2) void mamba_combine(
    const float* __restrict__ x_raw, const float* __restrict__ x_features,
    const float* __restrict__ embed_W, const float* __restrict__ embed_b,
    const float* __restrict__ in_W, const float* __restrict__ xproj_W,
    const float* __restrict__ A_log, const float* __restrict__ Dvec,
    const float* __restrict__ out_W,
    const float* __restrict__ mlp_W1, const float* __restrict__ mlp_b1,
    const float* __restrict__ mlp_W2, const float* __restrict__ mlp_b2,
    const float* __restrict__ head_W, const float* __restrict__ head_b,
    const float* __restrict__ ws_h, const float* __restrict__ ws_delta,
    const float* __restrict__ ws_xclast,
    float* __restrict__ out)
{
    __shared__ float xcl[DINNER], zs[DINNER], Cl[DSTATE], yv[DINNER];
    __shared__ float hfin[96], mlph[MLPH];

    const int tid = threadIdx.x;
    const int b   = blockIdx.x;
    const int dB  = tid >> 1;
    const int n0  = (tid & 1) * 8;

    bool structured = true;
    float Areg[8];
    #pragma unroll
    for (int i = 0; i < 8; ++i) {
        float a = __expf(A_log[dB*DSTATE + n0 + i]);
        float expect = (float)(n0 + i + 1);
        structured = structured && (fabsf(a - expect) < 1e-3f * expect);
        Areg[i] = -a;
    }

    float dd[NSEG];
    #pragma unroll
    for (int s2 = 1; s2 < NSEG; ++s2)
        dd[s2] = ws_delta[(b*NSEG + s2)*DINNER + dB];

    float hc[8];
    {
        const float4* hp = (const float4*)
            &ws_h[((size_t)b*NSEG + NSEG-1)*(DINNER*DSTATE) + dB*DSTATE + n0];
        float4 a = hp[0], c = hp[1];
        hc[0]=a.x; hc[1]=a.y; hc[2]=a.z; hc[3]=a.w;
        hc[4]=c.x; hc[5]=c.y; hc[6]=c.z; hc[7]=c.w;
    }
    float S = 0.f;
    for (int s2 = NSEG-2; s2 >= 0; --s2) {
        S += dd[s2+1];
        const float4* hp = (const float4*)
            &ws_h[((size_t)b*NSEG + s2)*(DINNER*DSTATE) + dB*DSTATE + n0];
        float4 a = hp[0], c = hp[1];
        float hs[8] = {a.x,a.y,a.z,a.w,c.x,c.y,c.z,c.w};
        if (structured) {
            float q = __expf(-S);
            float q2=q*q, q3=q2*q, q4=q2*q2, q5=q4*q, q6=q4*q2, q7=q4*q3, q8=q4*q4;
            float qb = n0 ? q8 : 1.f;
            hc[0] = fmaf(q *qb, hs[0], hc[0]);
            hc[1] = fmaf(q2*qb, hs[1], hc[1]);
            hc[2] = fmaf(q3*qb, hs[2], hc[2]);
            hc[3] = fmaf(q4*qb, hs[3], hc[3]);
            hc[4] = fmaf(q5*qb, hs[4], hc[4]);
            hc[5] = fmaf(q6*qb, hs[5], hc[5]);
            hc[6] = fmaf(q7*qb, hs[6], hc[6]);
            hc[7] = fmaf(q8*qb, hs[7], hc[7]);
        } else {
            #pragma unroll
            for (int i = 0; i < 8; ++i)
                hc[i] = fmaf(__expf(Areg[i]*S), hs[i], hc[i]);
        }
    }

    // phase 1: xc_last, z-gate, MLP stage 1
    if (tid < DINNER) {
        xcl[tid] = ws_xclast[b*DINNER + tid];
        float a1 = 0.f, a0 = 0.f;
        for (int dm = 0; dm < DMODEL; ++dm) {
            float w = in_W[dm*(2*DINNER) + DINNER + tid];   // z-half cols
            a1 = fmaf(embed_W[dm], w, a1);
            a0 = fmaf(embed_b[dm], w, a0);
        }
        float zv = fmaf(x_raw[b*LOOKBACK + LOOKBACK-1], a1, a0);
        zs[tid] = silu_f(zv);
    } else if (tid < 192) {
        int j = tid - 128;
        float acc = mlp_b1[j];
        const float* xf = x_features + b*NFEAT;
        for (int f = 0; f < NFEAT; ++f) acc = fmaf(xf[f], mlp_W1[f*MLPH + j], acc);
        mlph[j] = fmaxf(acc, 0.f);
    }
    __syncthreads();

    // phase 2: C at t=335, MLP stage 2
    if (tid < DSTATE) {
        float acc = 0.f;
        for (int d = 0; d < DINNER; ++d)
            acc = fmaf(xcl[d], xproj_W[d*36 + 20 + tid], acc);
        Cl[tid] = acc;
    } else if (tid >= 32 && tid < 64) {
        int j = tid - 32;
        float acc = mlp_b2[j];
        for (int k = 0; k < MLPH; ++k) acc = fmaf(mlph[k], mlp_W2[k*32 + j], acc);
        hfin[64 + j] = acc;
    }
    __syncthreads();

    // phase 3: y = (h·C + xc_last*D) * silu(z)
    {
        float part = 0.f;
        #pragma unroll
        for (int i = 0; i < 8; ++i) part = fmaf(hc[i], Cl[n0 + i], part);
        float other = __shfl_xor(part, 1);
        if ((tid & 1) == 0) {
            float y = part + other + xcl[dB]*Dvec[dB];
            yv[dB] = y * zs[dB];
        }
    }
    __syncthreads();

    // phase 4: out projection
    if (tid < DMODEL) {
        float acc = 0.f;
        for (int d = 0; d < DINNER; ++d)
            acc = fmaf(yv[d], out_W[d*DMODEL + tid], acc);
        hfin[tid] = acc;
    }
    __syncthreads();

    // phase 5: head
    if (tid < HORIZON) {
        float acc = head_b[tid];
        for (int i = 0; i < 96; ++i)
            acc = fmaf(hfin[i], head_W[i*HORIZON + tid], acc);
        out[b*HORIZON + tid] = acc;
    }
}

template<int NSEG>
static void launch_impl(void* const* d_in, void* d_out, void* d_ws,
                        hipStream_t stream) {
    float* ws        = (float*)d_ws;
    float* ws_h      = ws;
    float* ws_delta  = ws + (size_t)BATCH*NSEG*DINNER*DSTATE;
    float* ws_xclast = ws_delta + (size_t)BATCH*NSEG*DINNER;

    mamba_part<NSEG><<<BATCH*NSEG, 256, 0, stream>>>(
        (const float*)d_in[0],  (const float*)d_in[2],  (const float*)d_in[3],
        (const float*)d_in[4],  (const float*)d_in[5],  (const float*)d_in[6],
        (const float*)d_in[7],  (const float*)d_in[8],  (const float*)d_in[9],
        (const float*)d_in[10],
        ws_h, ws_delta, ws_xclast);

    mamba_combine<NSEG><<<BATCH, 256, 0, stream>>>(
        (const float*)d_in[0],  (const float*)d_in[1],  (const float*)d_in[2],
        (const float*)d_in[3],  (const float*)d_in[4],  (const float*)d_in[7],
        (const float*)d_in[10], (const float*)d_in[11], (const float*)d_in[12],
        (const float*)d_in[13], (const float*)d_in[14], (const float*)d_in[15],
        (const float*)d_in[16], (const float*)d_in[17], (const float*)d_in[18],
        ws_h, ws_delta, ws_xclast,
        (float*)d_out);
}

extern "C" void kernel_launch(void* const* d_in, const int* in_sizes, int n_in,
                              void* d_out, int out_size, void* d_ws, size_t ws_size,
                              hipStream_t stream) {
    (void)in_sizes; (void)n_in; (void)out_size;
    auto need = [](int nseg) {
        return ((size_t)BATCH*nseg*DINNER*DSTATE + (size_t)BATCH*nseg*DINNER
                + (size_t)BATCH*DINNER) * sizeof(float);
    };
    if      (ws_size >= need(16)) launch_impl<16>(d_in, d_out, d_ws, stream);
    else if (ws_size >= need(8))  launch_impl<8>(d_in, d_out, d_ws, stream);
    else                          launch_impl<4>(d_in, d_out, d_ws, stream);
}

// Round 8
// 196.830 us; speedup vs baseline: 2.2836x; 1.1147x over previous
//
#include <hip/hip_runtime.h>
#include <math.h>

#define LOOKBACK 336
#define NFEAT    164
#define HORIZON  96
#define DMODEL   64
#define DSTATE   16
#define DINNER   128
#define MLPH     64
#define BATCH    512
#define XCP      132

typedef float v2f __attribute__((ext_vector_type(2)));

__device__ __forceinline__ float fast_rcp(float x) { return __builtin_amdgcn_rcpf(x); }
__device__ __forceinline__ float silu_f(float x) {
    return x * fast_rcp(1.f + __expf(-x));
}

// ws_pre layout: [0..127]=w1x [128..255]=w0x [256..383]=w1z [384..511]=w0z [512]=structured
#define PRE_ELEMS 640

// ============ kernel 0: one-block precompute (folds + structure flag) =======
__global__ __launch_bounds__(256) void precomp(
    const float* __restrict__ embed_W, const float* __restrict__ embed_b,
    const float* __restrict__ in_W,    const float* __restrict__ A_log,
    float* __restrict__ ws_pre)
{
    __shared__ int okflag;
    const int tid = threadIdx.x;
    if (tid == 0) okflag = 1;
    __syncthreads();
    bool ok = true;
    #pragma unroll
    for (int i = 0; i < 8; ++i) {            // 256*8 = 2048 = all of A_log
        int idx = tid*8 + i;
        float a = __expf(A_log[idx]);
        float ex = (float)((idx & 15) + 1);
        ok = ok && (fabsf(a - ex) < 1e-3f * ex);
    }
    if (!ok) atomicAnd(&okflag, 0);
    const int ch = tid & 127, zh = tid >> 7;   // zh=0: x-half, zh=1: z-half
    float a1 = 0.f, a0 = 0.f;
    for (int dm = 0; dm < DMODEL; ++dm) {
        float w = in_W[dm*(2*DINNER) + zh*DINNER + ch];
        a1 = fmaf(embed_W[dm], w, a1);
        a0 = fmaf(embed_b[dm], w, a0);
    }
    ws_pre[zh*256 + ch]       = a1;
    ws_pre[zh*256 + 128 + ch] = a0;
    __syncthreads();
    if (tid == 0) ws_pre[512] = okflag ? 1.f : 0.f;
}

// ============ kernel 1: 2 segments/block; conv + x_dbl + partial scan =======
template<int NSEG>
__global__ __launch_bounds__(256, 3) void mamba_part(
    const float* __restrict__ x_raw,
    const float* __restrict__ conv_W,  const float* __restrict__ conv_b,
    const float* __restrict__ xproj_W, const float* __restrict__ dt_W,
    const float* __restrict__ dt_b,    const float* __restrict__ A_log,
    const float* __restrict__ ws_pre,
    float* __restrict__ ws_h, float* __restrict__ ws_delta,
    float* __restrict__ ws_xclast)
{
    constexpr int SEG = LOOKBACK / NSEG;
    constexpr int NTG = (SEG + 1) / 2;         // A2 t-groups (2 rows each)
    __shared__ __align__(16) float xrl[2][SEG + 8];
    __shared__ __align__(16) float xprojT[20*XCP];
    __shared__ __align__(16) float xc[2][SEG*XCP];
    __shared__ __align__(16) float Bsh[2][SEG][DSTATE];
    __shared__ __align__(16) float dtraw[2][SEG][4];

    const int tid = threadIdx.x;
    const int bid = blockIdx.x;
    const int b  = bid / (NSEG/2), sp = bid % (NSEG/2);
    const int sh = tid >> 7;                   // segment of the pair (wave-uniform)
    const int ch = tid & 127;
    const int s  = sp*2 + sh;

    // ---- staging ----
    if (ch < SEG + 3) {
        int gt = s*SEG - 3 + ch;
        xrl[sh][ch] = (gt >= 0) ? x_raw[b*LOOKBACK + gt] : 0.f;
    }
    for (int idx = tid; idx < 20*DINNER; idx += 256) {
        int jj = idx >> 7, d = idx & 127;
        xprojT[jj*XCP + d] = xproj_W[d*36 + jj];
    }

    const float w1 = ws_pre[ch], w0 = ws_pre[128 + ch];
    const bool structured = (ws_pre[512] != 0.f);
    const float4 cw = *(const float4*)&conv_W[ch*4];
    const float  cb = conv_b[ch];
    const float dtw0 = dt_W[ch],       dtw1 = dt_W[128 + ch],
                dtw2 = dt_W[256 + ch], dtw3 = dt_W[384 + ch];
    const float dtb_r = dt_b[ch];
    __syncthreads();

    // ---- conv+silu: each thread does all SEG timesteps of its (ch, seg) ----
    {
        float* xw = &xc[sh][0];
        const float* xr = &xrl[sh][0];
        if (s == 0) {          // zero-padded conv input at sequence start
            for (int tt = 0; tt < SEG; ++tt) {
                float acc = cb;
                if (tt >= 3) acc = fmaf(fmaf(xr[tt],   w1, w0), cw.x, acc);
                if (tt >= 2) acc = fmaf(fmaf(xr[tt+1], w1, w0), cw.y, acc);
                if (tt >= 1) acc = fmaf(fmaf(xr[tt+2], w1, w0), cw.z, acc);
                acc = fmaf(fmaf(xr[tt+3], w1, w0), cw.w, acc);
                xw[tt*XCP + ch] = silu_f(acc);
            }
        } else {               // sliding-window embed reuse
            float e0 = fmaf(xr[0], w1, w0);
            float e1 = fmaf(xr[1], w1, w0);
            float e2 = fmaf(xr[2], w1, w0);
            float v = 0.f;
            for (int tt = 0; tt < SEG; ++tt) {
                float e3 = fmaf(xr[tt+3], w1, w0);
                float acc = cb + e0*cw.x + e1*cw.y + e2*cw.z + e3*cw.w;
                v = silu_f(acc);
                xw[tt*XCP + ch] = v;
                e0 = e1; e1 = e2; e2 = e3;
            }
            if (s == NSEG-1) ws_xclast[b*DINNER + ch] = v;   // t = 335
        }
    }
    __syncthreads();

    // ---- A2: [SEG x 128] @ [128 x 20], 2t x 2j register tiles ----
    for (int task = ch; task < NTG*10; task += 128) {
        const int tg = task / 10;
        const int jp = task - tg*10;
        const int t0 = tg*2;
        const int t1 = (t0+1 < SEG) ? t0+1 : t0;
        const int j0 = jp*2;
        const float* p0 = &xprojT[j0*XCP];
        const float* p1 = &xprojT[(j0+1)*XCP];
        const float* x0 = &xc[sh][t0*XCP];
        const float* x1 = &xc[sh][t1*XCP];
        v2f a00 = {0,0}, a01 = {0,0}, a10 = {0,0}, a11 = {0,0};
        #pragma unroll 8
        for (int d = 0; d < DINNER; d += 4) {
            float4 xv0 = *(const float4*)(x0 + d);
            float4 xv1 = *(const float4*)(x1 + d);
            float4 q0  = *(const float4*)(p0 + d);
            float4 q1  = *(const float4*)(p1 + d);
            v2f x0l = {xv0.x, xv0.y}, x0h = {xv0.z, xv0.w};
            v2f x1l = {xv1.x, xv1.y}, x1h = {xv1.z, xv1.w};
            v2f q0l = {q0.x, q0.y},   q0h = {q0.z, q0.w};
            v2f q1l = {q1.x, q1.y},   q1h = {q1.z, q1.w};
            a00 = __builtin_elementwise_fma(x0l, q0l, a00);
            a00 = __builtin_elementwise_fma(x0h, q0h, a00);
            a01 = __builtin_elementwise_fma(x0l, q1l, a01);
            a01 = __builtin_elementwise_fma(x0h, q1h, a01);
            a10 = __builtin_elementwise_fma(x1l, q0l, a10);
            a10 = __builtin_elementwise_fma(x1h, q0h, a10);
            a11 = __builtin_elementwise_fma(x1l, q1l, a11);
            a11 = __builtin_elementwise_fma(x1h, q1h, a11);
        }
        float r00 = a00.x + a00.y, r01 = a01.x + a01.y;
        float r10 = a10.x + a10.y, r11 = a11.x + a11.y;
        if (j0 < 4) {
            *(float2*)&dtraw[sh][t0][j0] = make_float2(r00, r01);
            if (t1 != t0) *(float2*)&dtraw[sh][t1][j0] = make_float2(r10, r11);
        } else {
            *(float2*)&Bsh[sh][t0][j0-4] = make_float2(r00, r01);
            if (t1 != t0) *(float2*)&Bsh[sh][t1][j0-4] = make_float2(r10, r11);
        }
    }
    __syncthreads();

    // ---- scan: 1 lane per (ch, seg), all 16 states, v2f-packed ----
    const size_t obase = ((size_t)(b*NSEG + s))*(DINNER*DSTATE) + (size_t)ch*DSTATE;
    float dacc = 0.f;
    const float* xs = &xc[sh][0];
    if (__builtin_expect(structured, 1)) {
        v2f h01={0,0},h23={0,0},h45={0,0},h67={0,0},
            h89={0,0},hAB={0,0},hCD={0,0},hEF={0,0};
        #pragma unroll
        for (int tt = 0; tt < SEG; ++tt) {
            float4 dr = *(const float4*)&dtraw[sh][tt][0];       // broadcast
            float dv = fmaf(dr.x, dtw0, fmaf(dr.y, dtw1,
                       fmaf(dr.z, dtw2, fmaf(dr.w, dtw3, dtb_r))));
            float e  = __expf(dv);
            float p  = 1.f + e;
            float r  = fast_rcp(p);                  // exp(-delta)
            float dl = (dv > 80.f) ? dv : __logf(p); // delta
            dacc += dl;
            float ux = dl * xs[tt*XCP + ch];
            float4 B0 = *(const float4*)&Bsh[sh][tt][0];
            float4 B1 = *(const float4*)&Bsh[sh][tt][4];
            float4 B2 = *(const float4*)&Bsh[sh][tt][8];
            float4 B3 = *(const float4*)&Bsh[sh][tt][12];
            float r2 = r*r;
            v2f r2v = {r2, r2};
            v2f p01 = {r, r2};
            v2f p23 = p01*r2v, p45 = p23*r2v, p67 = p45*r2v, p89 = p67*r2v,
                pAB = p89*r2v, pCD = pAB*r2v, pEF = pCD*r2v;
            v2f uxv = {ux, ux};
            h01 = __builtin_elementwise_fma(p01, h01, uxv*(v2f){B0.x,B0.y});
            h23 = __builtin_elementwise_fma(p23, h23, uxv*(v2f){B0.z,B0.w});
            h45 = __builtin_elementwise_fma(p45, h45, uxv*(v2f){B1.x,B1.y});
            h67 = __builtin_elementwise_fma(p67, h67, uxv*(v2f){B1.z,B1.w});
            h89 = __builtin_elementwise_fma(p89, h89, uxv*(v2f){B2.x,B2.y});
            hAB = __builtin_elementwise_fma(pAB, hAB, uxv*(v2f){B2.z,B2.w});
            hCD = __builtin_elementwise_fma(pCD, hCD, uxv*(v2f){B3.x,B3.y});
            hEF = __builtin_elementwise_fma(pEF, hEF, uxv*(v2f){B3.z,B3.w});
        }
        float4* hp = (float4*)&ws_h[obase];
        hp[0] = make_float4(h01.x,h01.y,h23.x,h23.y);
        hp[1] = make_float4(h45.x,h45.y,h67.x,h67.y);
        hp[2] = make_float4(h89.x,h89.y,hAB.x,hAB.y);
        hp[3] = make_float4(hCD.x,hCD.y,hEF.x,hEF.y);
    } else {
        // generic fallback (not taken with reference inputs)
        float hv[16];
        #pragma unroll
        for (int i = 0; i < 16; ++i) hv[i] = 0.f;
        const float* Arow = A_log + ch*DSTATE;
        for (int tt = 0; tt < SEG; ++tt) {
            float4 dr = *(const float4*)&dtraw[sh][tt][0];
            float dv = fmaf(dr.x, dtw0, fmaf(dr.y, dtw1,
                       fmaf(dr.z, dtw2, fmaf(dr.w, dtw3, dtb_r))));
            float e  = __expf(dv);
            float dl = (dv > 15.f) ? dv : __logf(1.f + e);
            dacc += dl;
            float ux = dl * xs[tt*XCP + ch];
            const float* Brow = &Bsh[sh][tt][0];
            for (int i = 0; i < 16; ++i)
                hv[i] = fmaf(__expf(-__expf(Arow[i])*dl), hv[i], ux*Brow[i]);
        }
        float4* hp = (float4*)&ws_h[obase];
        hp[0] = make_float4(hv[0], hv[1], hv[2], hv[3]);
        hp[1] = make_float4(hv[4], hv[5], hv[6], hv[7]);
        hp[2] = make_float4(hv[8], hv[9], hv[10],hv[11]);
        hp[3] = make_float4(hv[12],hv[13],hv[14],hv[15]);
    }
    ws_delta[(b*NSEG + s)*DINNER + ch] = dacc;
}

// ============ kernel 2: combine segments + epilogue + MLP + head ============
template<int NSEG>
__global__ __launch_bounds__(256, 2) void mamba_combine(
    const float* __restrict__ x_raw, const float* __restrict__ x_features,
    const float* __restrict__ xproj_W, const float* __restrict__ A_log,
    const float* __restrict__ Dvec, const float* __restrict__ out_W,
    const float* __restrict__ mlp_W1, const float* __restrict__ mlp_b1,
    const float* __restrict__ mlp_W2, const float* __restrict__ mlp_b2,
    const float* __restrict__ head_W, const float* __restrict__ head_b,
    const float* __restrict__ ws_h, const float* __restrict__ ws_delta,
    const float* __restrict__ ws_xclast, const float* __restrict__ ws_pre,
    float* __restrict__ out)
{
    __shared__ float xcl[DINNER], zs[DINNER], Cl[DSTATE], yv[DINNER];
    __shared__ float hfin[96], mlph[MLPH];

    const int tid = threadIdx.x;
    const int b   = blockIdx.x;
    const int dB  = tid >> 1;
    const int n0  = (tid & 1) * 8;
    const bool structured = (ws_pre[512] != 0.f);

    // ---- combine partial h over segments (suffix delta sums) ----
    float dd[NSEG];
    #pragma unroll
    for (int s2 = 1; s2 < NSEG; ++s2)
        dd[s2] = ws_delta[(b*NSEG + s2)*DINNER + dB];
    float hc[8];
    {
        const float4* hp = (const float4*)
            &ws_h[((size_t)b*NSEG + NSEG-1)*(DINNER*DSTATE) + dB*DSTATE + n0];
        float4 a = hp[0], c = hp[1];
        hc[0]=a.x; hc[1]=a.y; hc[2]=a.z; hc[3]=a.w;
        hc[4]=c.x; hc[5]=c.y; hc[6]=c.z; hc[7]=c.w;
    }
    float S = 0.f;
    for (int s2 = NSEG-2; s2 >= 0; --s2) {
        S += dd[s2+1];
        const float4* hp = (const float4*)
            &ws_h[((size_t)b*NSEG + s2)*(DINNER*DSTATE) + dB*DSTATE + n0];
        float4 a = hp[0], c = hp[1];
        float hs[8] = {a.x,a.y,a.z,a.w,c.x,c.y,c.z,c.w};
        if (structured) {
            float q = __expf(-S);
            float q2=q*q, q3=q2*q, q4=q2*q2, q5=q4*q, q6=q4*q2, q7=q4*q3, q8=q4*q4;
            float qb = n0 ? q8 : 1.f;
            hc[0]=fmaf(q *qb,hs[0],hc[0]); hc[1]=fmaf(q2*qb,hs[1],hc[1]);
            hc[2]=fmaf(q3*qb,hs[2],hc[2]); hc[3]=fmaf(q4*qb,hs[3],hc[3]);
            hc[4]=fmaf(q5*qb,hs[4],hc[4]); hc[5]=fmaf(q6*qb,hs[5],hc[5]);
            hc[6]=fmaf(q7*qb,hs[6],hc[6]); hc[7]=fmaf(q8*qb,hs[7],hc[7]);
        } else {
            #pragma unroll
            for (int i = 0; i < 8; ++i)
                hc[i] = fmaf(__expf(-__expf(A_log[dB*DSTATE+n0+i])*S), hs[i], hc[i]);
        }
    }

    // ---- ph1: xcl/zs + mlp1 (tid<128, lane-pair split); C (wave 3) ----
    if (tid < 128) {
        xcl[tid] = ws_xclast[b*DINNER + tid];
        float zv = fmaf(x_raw[b*LOOKBACK + LOOKBACK-1],
                        ws_pre[256 + tid], ws_pre[384 + tid]);
        zs[tid] = silu_f(zv);
        // mlp1: j = tid>>1, k = tid&1 over 82-element halves (164 = 2*82)
        const int j = tid >> 1, k = tid & 1;
        const float* xf = x_features + b*NFEAT;
        float acc = 0.f;
        const int f0 = k*82, f1 = (k ? NFEAT : 82);
        for (int f = f0; f < f1; ++f)
            acc = fmaf(xf[f], mlp_W1[f*MLPH + j], acc);
        acc += __shfl_xor(acc, 1);
        if (k == 0) mlph[j] = fmaxf(acc + mlp_b1[j], 0.f);
    } else if (tid >= 192) {
        // C at t=335: lane = tid-192; n = lane&15, chunk q = lane>>4 (4x32)
        const int lane = tid - 192;
        const int n = lane & 15, q = lane >> 4;
        const float* xw = ws_xclast + b*DINNER;
        float acc = 0.f;
        for (int d = q*32; d < q*32 + 32; ++d)
            acc = fmaf(xw[d], xproj_W[d*36 + 20 + n], acc);
        acc += __shfl_xor(acc, 16);
        acc += __shfl_xor(acc, 32);
        if (lane < 16) Cl[n] = acc;
    }
    __syncthreads();

    // ---- ph2: mlp2 (tid<64, lane-pair split over k-halves) ----
    if (tid < 64) {
        const int j = tid >> 1, k = tid & 1;
        float acc = 0.f;
        for (int kk = k*32; kk < k*32 + 32; ++kk)
            acc = fmaf(mlph[kk], mlp_W2[kk*32 + j], acc);
        acc += __shfl_xor(acc, 1);
        if (k == 0) hfin[64 + j] = acc + mlp_b2[j];
    }
    __syncthreads();

    // ---- ph3: y = (h·C + xc_last*D) * silu(z) ----
    {
        float part = 0.f;
        #pragma unroll
        for (int i = 0; i < 8; ++i) part = fmaf(hc[i], Cl[n0 + i], part);
        float other = __shfl_xor(part, 1);
        if ((tid & 1) == 0) {
            float y = part + other + xcl[dB]*Dvec[dB];
            yv[dB] = y * zs[dB];
        }
    }
    __syncthreads();

    // ---- ph4: out projection, o = tid>>2, k = tid&3 (4x32 chunks) ----
    {
        const int o = tid >> 2, k = tid & 3;
        float acc = 0.f;
        for (int d = k*32; d < k*32 + 32; ++d)
            acc = fmaf(yv[d], out_W[d*DMODEL + o], acc);
        acc += __shfl_xor(acc, 1);
        acc += __shfl_xor(acc, 2);
        if (k == 0) hfin[o] = acc;
    }
    __syncthreads();

    // ---- ph5: head, o = tid>>1, k = tid&1 (2x48 chunks) ----
    if (tid < 192) {
        const int o = tid >> 1, k = tid & 1;
        float acc = 0.f;
        for (int i = k*48; i < k*48 + 48; ++i)
            acc = fmaf(hfin[i], head_W[i*HORIZON + o], acc);
        acc += __shfl_xor(acc, 1);
        if (k == 0) out[b*HORIZON + o] = acc + head_b[o];
    }
}

template<int NSEG>
static void launch_impl(void* const* d_in, void* d_out, void* d_ws,
                        hipStream_t stream) {
    float* ws        = (float*)d_ws;
    float* ws_h      = ws;
    float* ws_delta  = ws_h + (size_t)BATCH*NSEG*DINNER*DSTATE;
    float* ws_xclast = ws_delta + (size_t)BATCH*NSEG*DINNER;
    float* ws_pre    = ws_xclast + (size_t)BATCH*DINNER;

    precomp<<<1, 256, 0, stream>>>(
        (const float*)d_in[2], (const float*)d_in[3],
        (const float*)d_in[4], (const float*)d_in[10], ws_pre);

    mamba_part<NSEG><<<BATCH*NSEG/2, 256, 0, stream>>>(
        (const float*)d_in[0], (const float*)d_in[5], (const float*)d_in[6],
        (const float*)d_in[7], (const float*)d_in[8], (const float*)d_in[9],
        (const float*)d_in[10], ws_pre, ws_h, ws_delta, ws_xclast);

    mamba_combine<NSEG><<<BATCH, 256, 0, stream>>>(
        (const float*)d_in[0],  (const float*)d_in[1],  (const float*)d_in[7],
        (const float*)d_in[10], (const float*)d_in[11], (const float*)d_in[12],
        (const float*)d_in[13], (const float*)d_in[14], (const float*)d_in[15],
        (const float*)d_in[16], (const float*)d_in[17], (const float*)d_in[18],
        ws_h, ws_delta, ws_xclast, ws_pre,
        (float*)d_out);
}

extern "C" void kernel_launch(void* const* d_in, const int* in_sizes, int n_in,
                              void* d_out, int out_size, void* d_ws, size_t ws_size,
                              hipStream_t stream) {
    (void)in_sizes; (void)n_in; (void)out_size;
    auto need = [](int nseg) {
        return ((size_t)BATCH*nseg*DINNER*DSTATE + (size_t)BATCH*nseg*DINNER
                + (size_t)BATCH*DINNER + PRE_ELEMS) * sizeof(float);
    };
    if (ws_size >= need(16)) launch_impl<16>(d_in, d_out, d_ws, stream);
    else                     launch_impl<8>(d_in, d_out, d_ws, stream);
}